// Round 2
// baseline (323.595 us; speedup 1.0000x reference)
//
#include <hip/hip_runtime.h>
#include <cstdint>
#include <cstddef>

typedef float f32x4 __attribute__((ext_vector_type(4)));
typedef long  lx2   __attribute__((ext_vector_type(2)));

#define PXB 1024   // partial-max blocks for x
#define PWB 64     // partial-max blocks for w
#define QWB 64     // quant blocks for w

// ---------------------------------------------------------------------------
// helpers
// ---------------------------------------------------------------------------
__device__ __forceinline__ void async_copy16(const uint8_t* g, uint8_t* s) {
    __builtin_amdgcn_global_load_lds(
        (const __attribute__((address_space(1))) void*)g,
        (__attribute__((address_space(3))) void*)s,
        16 /*bytes*/, 0 /*offset*/, 0 /*aux*/);
}

// Raw barrier with counted vmcnt: leaves N youngest vector-mem ops in
// flight (our 8 register A-prefetch loads), drains everything older (the
// 2 global_load_lds B stages) and all DS ops (so our ds_writes are visible
// to the other waves). sched_barrier(0) fences compiler code motion
// (rule: "memory" clobber does not order register-only MFMA).
#define BARRIER_VM(N)                                                     \
    do {                                                                  \
        asm volatile("s_waitcnt vmcnt(" #N ") lgkmcnt(0)" ::: "memory");  \
        __builtin_amdgcn_sched_barrier(0);                                \
        __builtin_amdgcn_s_barrier();                                     \
        __builtin_amdgcn_sched_barrier(0);                                \
    } while (0)

// block-wide max; every thread returns the result. Caller must not reuse
// scr until after a subsequent __syncthreads().
__device__ __forceinline__ float block_max(float m, float* scr) {
#pragma unroll
    for (int o = 32; o > 0; o >>= 1) m = fmaxf(m, __shfl_down(m, o, 64));
    const int lane = threadIdx.x & 63, wid = threadIdx.x >> 6;
    if (lane == 0) scr[wid] = m;
    __syncthreads();
    const int nw = blockDim.x >> 6;
    m = scr[0];
    for (int j = 1; j < nw; ++j) m = fmaxf(m, scr[j]);
    return m;
}

// ---------------------------------------------------------------------------
// 1. per-block amax partials (no atomics, no init kernel needed)
//    blocks [0,PXB) -> x, partials part[0..PXB); blocks [PXB,PXB+PWB) -> w
// ---------------------------------------------------------------------------
__global__ void amax_partials(const float4* __restrict__ x, int nx4,
                              const float4* __restrict__ w, int nw4,
                              float* __restrict__ part) {
    __shared__ float scr[8];
    const int b = blockIdx.x;
    const float4* p;
    int n4, nb, bi;
    if (b < PXB) { p = x; n4 = nx4; nb = PXB; bi = b; }
    else         { p = w; n4 = nw4; nb = PWB; bi = b - PXB; }
    float m = 0.0f;
    for (int i = bi * blockDim.x + threadIdx.x; i < n4; i += nb * blockDim.x) {
        float4 v = p[i];
        m = fmaxf(m, fmaxf(fmaxf(fabsf(v.x), fabsf(v.y)),
                           fmaxf(fabsf(v.z), fabsf(v.w))));
    }
    m = block_max(m, scr);
    if (threadIdx.x == 0) part[b] = m;
}

// ---------------------------------------------------------------------------
// 2. quantize w only (tiny: 4 MB read, 1 MB write). x is quantized inside
//    the GEMM; w is quantized once here because all 256 M-panels reuse it.
// ---------------------------------------------------------------------------
__global__ void quant_w_kernel(const float4* __restrict__ w, int nw16,
                               const float* __restrict__ part,
                               int4* __restrict__ wq) {
    __shared__ float scr[8];
    float m = 0.0f;
    for (int i = threadIdx.x; i < PWB; i += blockDim.x)
        m = fmaxf(m, part[PXB + i]);
    m = block_max(m, scr);
    const float r = 1.0f / fmaxf(m / 448.0f, 1e-12f);

    for (int i = blockIdx.x * blockDim.x + threadIdx.x; i < nw16;
         i += QWB * blockDim.x) {
        int4 o;
#pragma unroll
        for (int j = 0; j < 4; ++j) {
            float4 v = w[i * 4 + j];
            int p = 0;
            p = __builtin_amdgcn_cvt_pk_fp8_f32(v.x * r, v.y * r, p, false);
            p = __builtin_amdgcn_cvt_pk_fp8_f32(v.z * r, v.w * r, p, true);
            ((int*)&o)[j] = p;
        }
        wq[i] = o;
    }
}

// ---------------------------------------------------------------------------
// 3. fp8 GEMM with fused x-quantization, double-buffered LDS, ONE raw
//    barrier per K-step with counted vmcnt (register A-prefetch stays in
//    flight across the barrier -- the T4 counted-vmcnt pipeline).
//    C[m,n] = (sum_k q(A32[m,k]) * B[n,k]) * scale + bias[n]
//    128x128 tile, BK=64, 256 thr (4 waves 2x2, each 64x64 via 4x4 MFMA).
//    Numerics byte-identical to the verified round-1 kernel; only the
//    schedule changed.
//    Race-freedom: writes to buf^1 at iter t start after barrier(t-1)
//    (all waves' reads of buf^1 completed before it -- ds reads complete
//    in-order before their MFMA consumers) and are drained by the
//    lgkmcnt(0) in barrier(t). B's global_load_lds are the 2 OLDEST vmem
//    ops at barrier(t): vmcnt(8) drains exactly them, leaving only the 8
//    register loads (which write no LDS) in flight.
// ---------------------------------------------------------------------------
__global__ __launch_bounds__(256) void gemm_fp8_kernel(
    const float* __restrict__ A32,   // [M][K] fp32 (x)
    const uint8_t* __restrict__ B,   // [N][K] fp8 (w)
    const float* __restrict__ bias,  // [N]
    const float* __restrict__ part,  // amax partials
    float* __restrict__ out,         // [M][N] fp32
    int M, int N, int K) {
    // 32 KiB tiles: buf0 = A[0..1023]+B[1024..2047], buf1 = [2048..4095]
    // (long units, 8 B each). +16 longs dedicated scr so the scale phase
    // does not alias the tile buffers.
    __shared__ long lds64[4112];

    const int tid  = threadIdx.x;
    const int l    = tid & 63;
    const int w    = tid >> 6;
    const int lm   = l & 15;
    const int quad = l >> 4;
    const int wm   = (w >> 1) * 64;  // wave's M offset in tile
    const int wn   = (w & 1) * 64;   // wave's N offset in tile

    // XCD-aware swizzle: linear id = bx + 8*by, HW round-robins XCD by id%8.
    // Remap so an A panel's 8 blocks share one XCD's L2 (FETCH 133->80 MB).
    int bx = blockIdx.x, by = blockIdx.y;
    if (gridDim.x == 8) {
        const int lin = blockIdx.x + (blockIdx.y << 3);
        const int c0 = lin & 7;       // physical XCD
        const int k0 = lin >> 3;      // 0..gridDim.y-1
        bx = k0 & 7;
        by = (k0 & ~7) | c0;
    }
    const size_t am0 = (size_t)by * 128;
    const size_t bn0 = (size_t)bx * 128;

    // A staging geometry: thread t owns 4 fp8 bytes per row, 8 rows/K-step.
    const int arow = tid >> 4;          // 0..15 (row within 16-row group)
    const int acol = (tid & 15) * 4;    // K offset (floats) within 64
    const float* aptr = A32 + (am0 + arow) * (size_t)K + acol;

    // prologue A loads issued first: HBM latency overlaps the partials
    // reduction below (its internal __syncthreads drains them once; fine).
    f32x4 av[8];
#pragma unroll
    for (int j = 0; j < 8; ++j)
        av[j] = *(const f32x4*)(aptr + (size_t)j * 16 * K);

    // per-tensor scales from partials (dedicated scr region; no barrier
    // needed afterwards -- tile buffers are disjoint).
    float* scr = (float*)&lds64[4096];
    float mx = 0.0f, mw = 0.0f;
    for (int i = tid; i < PXB; i += 256) mx = fmaxf(mx, part[i]);
    for (int i = tid; i < PWB; i += 256) mw = fmaxf(mw, part[PXB + i]);
    mx = block_max(mx, scr);
    mw = block_max(mw, scr + 8);
    const float sx = fmaxf(mx / 448.0f, 1e-12f);
    const float sw = fmaxf(mw / 448.0f, 1e-12f);
    const float scale = sx * sw;
    const float rq = 1.0f / sx;      // x quant multiplier (matches reference)

    f32x4 acc[4][4];
#pragma unroll
    for (int i = 0; i < 4; ++i)
#pragma unroll
        for (int j = 0; j < 4; ++j) acc[i][j] = (f32x4)0.0f;

    const int slot0 = w * 64 + l;  // 0..255; slot s -> row s/4, 16B-chunk s%4

    // ---- prologue: stage tile 0 into buf0, issue av for tile 1 ----
    {
        uint8_t* A0 = (uint8_t*)lds64;
        uint8_t* B0 = (uint8_t*)(lds64 + 1024);
#pragma unroll
        for (int i = 0; i < 2; ++i) {
            const int s = i * 256 + slot0;
            async_copy16(B + (bn0 + (s >> 2)) * (size_t)K + (s & 3) * 16,
                         B0 + (i * 4 + w) * 1024);
        }
#pragma unroll
        for (int j = 0; j < 8; ++j) {
            int p = 0;
            p = __builtin_amdgcn_cvt_pk_fp8_f32(av[j].x * rq, av[j].y * rq, p, false);
            p = __builtin_amdgcn_cvt_pk_fp8_f32(av[j].z * rq, av[j].w * rq, p, true);
            *(int*)(A0 + (j * 16 + arow) * 64 + acol) = p;
        }
#pragma unroll
        for (int j = 0; j < 8; ++j)
            av[j] = *(const f32x4*)(aptr + 64 + (size_t)j * 16 * K);
        BARRIER_VM(8);
    }

    // ---- main loop: one raw barrier per K-step ----
    int c = 0;
    for (int kt = 0; kt < K; kt += 64) {
        long* Ab = lds64 + (c ? 2048 : 0);
        long* Bb = Ab + 1024;
        const bool haveNext = (kt + 64 < K);

        if (haveNext) {
            uint8_t* An = (uint8_t*)(lds64 + (c ? 0 : 2048));
            uint8_t* Bn = An + 8192;
            // B: async global->LDS for next tile (oldest vmem ops at barrier)
#pragma unroll
            for (int i = 0; i < 2; ++i) {
                const int s = i * 256 + slot0;
                async_copy16(B + (bn0 + (s >> 2)) * (size_t)K + (kt + 64) + (s & 3) * 16,
                             Bn + (i * 4 + w) * 1024);
            }
            // A: convert prefetched fp32 regs -> fp8, write next buffer.
#pragma unroll
            for (int j = 0; j < 8; ++j) {
                int p = 0;
                p = __builtin_amdgcn_cvt_pk_fp8_f32(av[j].x * rq, av[j].y * rq, p, false);
                p = __builtin_amdgcn_cvt_pk_fp8_f32(av[j].z * rq, av[j].w * rq, p, true);
                *(int*)(An + (j * 16 + arow) * 64 + acol) = p;
            }
            // issue av for tile kt+128 (stays in flight across the barrier)
            if (kt + 128 < K) {
#pragma unroll
                for (int j = 0; j < 8; ++j)
                    av[j] = *(const f32x4*)(aptr + (kt + 128) + (size_t)j * 16 * K);
            }
        }

        lx2 a[4], b[4];
#pragma unroll
        for (int t = 0; t < 4; ++t) {
            a[t] = *(const lx2*)&Ab[(wm + t * 16 + lm) * 8 + quad * 2];
            b[t] = *(const lx2*)&Bb[(wn + t * 16 + lm) * 8 + quad * 2];
        }
        __builtin_amdgcn_s_setprio(1);
#pragma unroll
        for (int ks = 0; ks < 2; ++ks)
#pragma unroll
            for (int mt = 0; mt < 4; ++mt)
#pragma unroll
                for (int nt = 0; nt < 4; ++nt)
                    acc[mt][nt] = __builtin_amdgcn_mfma_f32_16x16x32_fp8_fp8(
                        a[mt][ks], b[nt][ks], acc[mt][nt], 0, 0, 0);
        __builtin_amdgcn_s_setprio(0);

        if (haveNext) {
            if (kt + 128 < K) { BARRIER_VM(8); }
            else             { BARRIER_VM(0); }
        }
        c ^= 1;
    }

    // epilogue: D row = quad*4+reg, col = lm (within each 16x16 tile)
#pragma unroll
    for (int nt = 0; nt < 4; ++nt) {
        const int n = (int)bn0 + wn + nt * 16 + lm;
        const float bv = bias[n];
#pragma unroll
        for (int mt = 0; mt < 4; ++mt) {
            const size_t mrow = am0 + wm + mt * 16 + quad * 4;
#pragma unroll
            for (int r = 0; r < 4; ++r) {
                out[(mrow + r) * (size_t)N + n] = acc[mt][nt][r] * scale + bv;
            }
        }
    }
}

// ---------------------------------------------------------------------------
// host launcher
// ---------------------------------------------------------------------------
extern "C" void kernel_launch(void* const* d_in, const int* in_sizes, int n_in,
                              void* d_out, int out_size, void* d_ws,
                              size_t ws_size, hipStream_t stream) {
    const float* x      = (const float*)d_in[0];
    const float* weight = (const float*)d_in[1];
    const float* bias   = (const float*)d_in[2];
    float* out          = (float*)d_out;

    const int nx = in_sizes[0];        // M*K = 33554432
    const int nw = in_sizes[1];        // N*K = 1048576
    const int N  = in_sizes[2];        // 1024
    const int K  = nw / N;             // 1024
    const int M  = nx / K;             // 32768

    float* part     = (float*)d_ws;                 // PXB+PWB floats
    uint8_t* w_fp8  = (uint8_t*)d_ws + 8192;        // N*K fp8

    amax_partials<<<PXB + PWB, 256, 0, stream>>>(
        (const float4*)x, nx / 4, (const float4*)weight, nw / 4, part);
    quant_w_kernel<<<QWB, 256, 0, stream>>>(
        (const float4*)weight, nw / 16, part, (int4*)w_fp8);
    gemm_fp8_kernel<<<dim3(N / 128, M / 128), 256, 0, stream>>>(
        x, w_fp8, bias, part, out, M, N, K);
}

// Round 3
// 296.926 us; speedup vs baseline: 1.0898x; 1.0898x over previous
//
#include <hip/hip_runtime.h>
#include <cstdint>
#include <cstddef>

typedef float f32x4 __attribute__((ext_vector_type(4)));
typedef long  lx2   __attribute__((ext_vector_type(2)));

#define PXB 1024   // partial-max blocks for x
#define PWB 64     // partial-max blocks for w
#define QWB 64     // quant blocks for w

// ---------------------------------------------------------------------------
// helpers
// ---------------------------------------------------------------------------
__device__ __forceinline__ void async_copy16(const uint8_t* g, uint8_t* s) {
    __builtin_amdgcn_global_load_lds(
        (const __attribute__((address_space(1))) void*)g,
        (__attribute__((address_space(3))) void*)s,
        16 /*bytes*/, 0 /*offset*/, 0 /*aux*/);
}

// block-wide max; every thread returns the result. Caller must not reuse
// scr until after a subsequent __syncthreads().
__device__ __forceinline__ float block_max(float m, float* scr) {
#pragma unroll
    for (int o = 32; o > 0; o >>= 1) m = fmaxf(m, __shfl_down(m, o, 64));
    const int lane = threadIdx.x & 63, wid = threadIdx.x >> 6;
    if (lane == 0) scr[wid] = m;
    __syncthreads();
    const int nw = blockDim.x >> 6;
    m = scr[0];
    for (int j = 1; j < nw; ++j) m = fmaxf(m, scr[j]);
    return m;
}

// ---------------------------------------------------------------------------
// 1. per-block amax partials (no atomics, no init kernel needed)
//    blocks [0,PXB) -> x, partials part[0..PXB); blocks [PXB,PXB+PWB) -> w
// ---------------------------------------------------------------------------
__global__ void amax_partials(const float4* __restrict__ x, int nx4,
                              const float4* __restrict__ w, int nw4,
                              float* __restrict__ part) {
    __shared__ float scr[8];
    const int b = blockIdx.x;
    const float4* p;
    int n4, nb, bi;
    if (b < PXB) { p = x; n4 = nx4; nb = PXB; bi = b; }
    else         { p = w; n4 = nw4; nb = PWB; bi = b - PXB; }
    float m = 0.0f;
    for (int i = bi * blockDim.x + threadIdx.x; i < n4; i += nb * blockDim.x) {
        float4 v = p[i];
        m = fmaxf(m, fmaxf(fmaxf(fabsf(v.x), fabsf(v.y)),
                           fmaxf(fabsf(v.z), fabsf(v.w))));
    }
    m = block_max(m, scr);
    if (threadIdx.x == 0) part[b] = m;
}

// ---------------------------------------------------------------------------
// 2. quantize w only (tiny: 4 MB read, 1 MB write). x is quantized inside
//    the GEMM; w is quantized once here because all 256 M-panels reuse it.
// ---------------------------------------------------------------------------
__global__ void quant_w_kernel(const float4* __restrict__ w, int nw16,
                               const float* __restrict__ part,
                               int4* __restrict__ wq) {
    __shared__ float scr[8];
    float m = 0.0f;
    for (int i = threadIdx.x; i < PWB; i += blockDim.x)
        m = fmaxf(m, part[PXB + i]);
    m = block_max(m, scr);
    const float r = 1.0f / fmaxf(m / 448.0f, 1e-12f);

    for (int i = blockIdx.x * blockDim.x + threadIdx.x; i < nw16;
         i += QWB * blockDim.x) {
        int4 o;
#pragma unroll
        for (int j = 0; j < 4; ++j) {
            float4 v = w[i * 4 + j];
            int p = 0;
            p = __builtin_amdgcn_cvt_pk_fp8_f32(v.x * r, v.y * r, p, false);
            p = __builtin_amdgcn_cvt_pk_fp8_f32(v.z * r, v.w * r, p, true);
            ((int*)&o)[j] = p;
        }
        wq[i] = o;
    }
}

// ---------------------------------------------------------------------------
// 3. fp8 GEMM with fused x-quantization. Structure = verified round-1
//    kernel (single-buffer LDS, 2 compiler barriers per K-step -- the
//    hand-pipelined variant regressed: occupancy + sched-freedom loss).
//    NEW vs round-1: T2 LDS XOR-swizzle to kill the 8-way bank conflict
//    on the fragment ds_read_b128s.
//
//    Swizzle: physical 16B-chunk = logical chunk ^ ((row>>1)&3).
//    For this layout the XOR term is THREAD-CONSTANT everywhere:
//      - A ds_write: row = j*16+arow, (row>>1)&3 == (arow>>1)&3
//      - frag reads: row = base16 + lm,  (row>>1)&3 == (lm>>1)&3
//    so the swizzle costs ~2 VALU ops. B is staged via global_load_lds
//    (linear dest, can't swizzle) -> pre-swizzle the global SOURCE chunk
//    instead (same involution); 64B segments preserved, coalescing intact.
//    Reads: 16 same-quad lanes now cover all 8 bank-groups twice (2-way =
//    free) instead of 2 groups 8-way. Byte-permutation only: numerics
//    bit-identical.
// ---------------------------------------------------------------------------
__global__ __launch_bounds__(256) void gemm_fp8_kernel(
    const float* __restrict__ A32,   // [M][K] fp32 (x)
    const uint8_t* __restrict__ B,   // [N][K] fp8 (w)
    const float* __restrict__ bias,  // [N]
    const float* __restrict__ part,  // amax partials
    float* __restrict__ out,         // [M][N] fp32
    int M, int N, int K) {
    __shared__ long lds64[2048];     // 16 KiB: A tile [128][64B] + B tile
    uint8_t* Abase = (uint8_t*)lds64;

    const int tid  = threadIdx.x;
    const int l    = tid & 63;
    const int w    = tid >> 6;
    const int lm   = l & 15;
    const int quad = l >> 4;
    const int wm   = (w >> 1) * 64;  // wave's M offset in tile
    const int wn   = (w & 1) * 64;   // wave's N offset in tile

    // XCD-aware swizzle: linear id = bx + 8*by, HW round-robins XCD by id%8.
    // Remap so an A panel's 8 blocks share one XCD's L2 (FETCH 133->80 MB).
    int bx = blockIdx.x, by = blockIdx.y;
    if (gridDim.x == 8) {
        const int lin = blockIdx.x + (blockIdx.y << 3);
        const int c0 = lin & 7;       // physical XCD
        const int k0 = lin >> 3;      // 0..gridDim.y-1
        bx = k0 & 7;
        by = (k0 & ~7) | c0;
    }
    const size_t am0 = (size_t)by * 128;
    const size_t bn0 = (size_t)bx * 128;

    // A staging geometry: thread t owns 4 fp8 bytes per row, 8 rows/K-step.
    const int arow = tid >> 4;          // 0..15 (row within 16-row group)
    const int acol = (tid & 15) * 4;    // K offset (floats) within 64
    const float* aptr = A32 + (am0 + arow) * (size_t)K + acol;
    // swizzled A write offset within a row (thread-constant):
    const int awoff = ((((acol >> 4) ^ ((arow >> 1) & 3)) << 4) | (acol & 15));

    // prologue A loads issued first: HBM latency overlaps the partials
    // reduction below.
    f32x4 av[8];
#pragma unroll
    for (int j = 0; j < 8; ++j)
        av[j] = *(const f32x4*)(aptr + (size_t)j * 16 * K);

    // per-tensor scales from partials (cheap block-local reduction)
    float* scr = (float*)lds64;
    float mx = 0.0f, mw = 0.0f;
    for (int i = tid; i < PXB; i += 256) mx = fmaxf(mx, part[i]);
    for (int i = tid; i < PWB; i += 256) mw = fmaxf(mw, part[PXB + i]);
    mx = block_max(mx, scr);
    mw = block_max(mw, scr + 8);
    const float sx = fmaxf(mx / 448.0f, 1e-12f);
    const float sw = fmaxf(mw / 448.0f, 1e-12f);
    const float scale = sx * sw;
    const float rq = 1.0f / sx;      // x quant multiplier (matches reference)
    __syncthreads();  // scr reads done before staging overwrites LDS

    f32x4 acc[4][4];
#pragma unroll
    for (int i = 0; i < 4; ++i)
#pragma unroll
        for (int j = 0; j < 4; ++j) acc[i][j] = (f32x4)0.0f;

    const int slot0 = w * 64 + l;  // 0..255; slot s -> row s/4, 16B-chunk s%4
    // swizzled fragment chunk (thread-constant), in long units (8B):
    const int fchunk = (quad ^ ((lm >> 1) & 3)) << 1;

    for (int kt = 0; kt < K; kt += 64) {
        // B: async global->LDS. Dest is linear; SOURCE chunk pre-swizzled so
        // LDS holds the swizzled layout.
#pragma unroll
        for (int i = 0; i < 2; ++i) {
            const int s    = i * 256 + slot0;
            const int row  = s >> 2;
            const int chnk = (s & 3) ^ ((row >> 1) & 3);
            async_copy16(B + (bn0 + row) * (size_t)K + kt + chnk * 16,
                         Abase + 8192 + (i * 4 + w) * 1024);
        }
        // A: convert this K-step's prefetched fp32 regs -> fp8, write LDS
        // at the swizzled chunk. Writes stay conflict-free (16 lanes cover
        // a full permuted 64B row).
#pragma unroll
        for (int j = 0; j < 8; ++j) {
            f32x4 t = av[j] * rq;    // v_pk_mul_f32 x2
            int p = 0;
            p = __builtin_amdgcn_cvt_pk_fp8_f32(t.x, t.y, p, false);
            p = __builtin_amdgcn_cvt_pk_fp8_f32(t.z, t.w, p, true);
            *(int*)(Abase + (j * 16 + arow) * 64 + awoff) = p;
        }
        __syncthreads();

        lx2 a[4], b[4];
#pragma unroll
        for (int t = 0; t < 4; ++t) {
            a[t] = *(const lx2*)&lds64[(wm + t * 16 + lm) * 8 + fchunk];
            b[t] = *(const lx2*)&lds64[1024 + (wn + t * 16 + lm) * 8 + fchunk];
        }
        // prefetch next K-step's A (overlaps the MFMA phase; drained at the
        // trailing barrier, by which point MFMA has covered most latency)
        if (kt + 64 < K) {
            const float* ap = aptr + (kt + 64);
#pragma unroll
            for (int j = 0; j < 8; ++j)
                av[j] = *(const f32x4*)(ap + (size_t)j * 16 * K);
        }
#pragma unroll
        for (int ks = 0; ks < 2; ++ks)
#pragma unroll
            for (int mt = 0; mt < 4; ++mt)
#pragma unroll
                for (int nt = 0; nt < 4; ++nt)
                    acc[mt][nt] = __builtin_amdgcn_mfma_f32_16x16x32_fp8_fp8(
                        a[mt][ks], b[nt][ks], acc[mt][nt], 0, 0, 0);
        __syncthreads();
    }

    // epilogue: D row = quad*4+reg, col = lm (within each 16x16 tile)
#pragma unroll
    for (int nt = 0; nt < 4; ++nt) {
        const int n = (int)bn0 + wn + nt * 16 + lm;
        const float bv = bias[n];
#pragma unroll
        for (int mt = 0; mt < 4; ++mt) {
            const size_t mrow = am0 + wm + mt * 16 + quad * 4;
#pragma unroll
            for (int r = 0; r < 4; ++r) {
                out[(mrow + r) * (size_t)N + n] = acc[mt][nt][r] * scale + bv;
            }
        }
    }
}

// ---------------------------------------------------------------------------
// host launcher
// ---------------------------------------------------------------------------
extern "C" void kernel_launch(void* const* d_in, const int* in_sizes, int n_in,
                              void* d_out, int out_size, void* d_ws,
                              size_t ws_size, hipStream_t stream) {
    const float* x      = (const float*)d_in[0];
    const float* weight = (const float*)d_in[1];
    const float* bias   = (const float*)d_in[2];
    float* out          = (float*)d_out;

    const int nx = in_sizes[0];        // M*K = 33554432
    const int nw = in_sizes[1];        // N*K = 1048576
    const int N  = in_sizes[2];        // 1024
    const int K  = nw / N;             // 1024
    const int M  = nx / K;             // 32768

    float* part     = (float*)d_ws;                 // PXB+PWB floats
    uint8_t* w_fp8  = (uint8_t*)d_ws + 8192;        // N*K fp8

    amax_partials<<<PXB + PWB, 256, 0, stream>>>(
        (const float4*)x, nx / 4, (const float4*)weight, nw / 4, part);
    quant_w_kernel<<<QWB, 256, 0, stream>>>(
        (const float4*)weight, nw / 16, part, (int4*)w_fp8);
    gemm_fp8_kernel<<<dim3(N / 128, M / 128), 256, 0, stream>>>(
        x, w_fp8, bias, part, out, M, N, K);
}